// Round 3
// baseline (8267.504 us; speedup 1.0000x reference)
//
#include <hip/hip_runtime.h>
#include <hip/hip_bf16.h>

typedef float f32x4 __attribute__((ext_vector_type(4)));
typedef __bf16 bf16x8 __attribute__((ext_vector_type(8)));

using as1c_t = __attribute__((address_space(1))) const char;
using as3_t  = __attribute__((address_space(3))) char;

static __device__ __forceinline__ float sigmoidf_(float x) {
  return 1.f / (1.f + __expf(-x));
}
static __device__ __forceinline__ __bf16 bfc(float x) { return (__bf16)x; }

// ---------------- K1: r = gather(hidden) @ W_red + b_red ----------------
__global__ __launch_bounds__(256) void k_r(const float* __restrict__ hidden,
    const float* __restrict__ Wred, const float* __restrict__ bred,
    const int* __restrict__ cidx, float* __restrict__ r) {
  __shared__ float docsT[768][8];
  const int bx = blockIdx.x;
  const int b = bx >> 3, n0 = (bx & 7) * 8;
  const int t = threadIdx.x;
  #pragma unroll
  for (int g = 0; g < 8; ++g) {
    const int tok = cidx[b * 64 + n0 + g];
    const float* src = hidden + ((size_t)b * 512 + tok) * 768;
    for (int f = t; f < 768; f += 256) docsT[f][g] = src[f];
  }
  __syncthreads();
  float acc[8];
  #pragma unroll
  for (int g = 0; g < 8; ++g) acc[g] = bred[t];
  for (int f = 0; f < 768; ++f) {
    const float w = Wred[f * 256 + t];
    const float4 d0 = *(const float4*)&docsT[f][0];
    const float4 d1 = *(const float4*)&docsT[f][4];
    acc[0] = fmaf(d0.x, w, acc[0]); acc[1] = fmaf(d0.y, w, acc[1]);
    acc[2] = fmaf(d0.z, w, acc[2]); acc[3] = fmaf(d0.w, w, acc[3]);
    acc[4] = fmaf(d1.x, w, acc[4]); acc[5] = fmaf(d1.y, w, acc[5]);
    acc[6] = fmaf(d1.z, w, acc[6]); acc[7] = fmaf(d1.w, w, acc[7]);
  }
  #pragma unroll
  for (int g = 0; g < 8; ++g) r[((size_t)(b * 64 + n0 + g)) * 256 + t] = acc[g];
}

// ---------------- K2: Ai = r@Wcat[:256] + b_cat ; Aj = r@Wcat[256:] ----------------
__global__ __launch_bounds__(256) void k_ab(const float* __restrict__ r,
    const float* __restrict__ Wcat, const float* __restrict__ bcat,
    float* __restrict__ Ai, float* __restrict__ Aj) {
  __shared__ float rT[256][8];
  const int bx = blockIdx.x;
  const int b = bx >> 3, n0 = (bx & 7) * 8;
  const int t = threadIdx.x;
  #pragma unroll
  for (int g = 0; g < 8; ++g)
    rT[t][g] = r[((size_t)(b * 64 + n0 + g)) * 256 + t];
  __syncthreads();
  float ai[8], aj[8];
  #pragma unroll
  for (int g = 0; g < 8; ++g) { ai[g] = bcat[t]; aj[g] = 0.f; }
  for (int k = 0; k < 256; ++k) {
    const float w0 = Wcat[k * 256 + t];
    const float w1 = Wcat[(256 + k) * 256 + t];
    const float4 d0 = *(const float4*)&rT[k][0];
    const float4 d1 = *(const float4*)&rT[k][4];
    ai[0] = fmaf(d0.x, w0, ai[0]); aj[0] = fmaf(d0.x, w1, aj[0]);
    ai[1] = fmaf(d0.y, w0, ai[1]); aj[1] = fmaf(d0.y, w1, aj[1]);
    ai[2] = fmaf(d0.z, w0, ai[2]); aj[2] = fmaf(d0.z, w1, aj[2]);
    ai[3] = fmaf(d0.w, w0, ai[3]); aj[3] = fmaf(d0.w, w1, aj[3]);
    ai[4] = fmaf(d1.x, w0, ai[4]); aj[4] = fmaf(d1.x, w1, aj[4]);
    ai[5] = fmaf(d1.y, w0, ai[5]); aj[5] = fmaf(d1.y, w1, aj[5]);
    ai[6] = fmaf(d1.z, w0, ai[6]); aj[6] = fmaf(d1.z, w1, aj[6]);
    ai[7] = fmaf(d1.w, w0, ai[7]); aj[7] = fmaf(d1.w, w1, aj[7]);
  }
  #pragma unroll
  for (int g = 0; g < 8; ++g) {
    Ai[((size_t)(b * 64 + n0 + g)) * 256 + t] = ai[g];
    Aj[((size_t)(b * 64 + n0 + g)) * 256 + t] = aj[g];
  }
}

// ---------------- K3: WxT[n][k] = bf16(W_x[k][n]) ----------------
__global__ __launch_bounds__(256) void k_wt(const float* __restrict__ Wx,
                                            __hip_bfloat16* __restrict__ WxT) {
  const int n = blockIdx.x, k = threadIdx.x;
  WxT[n * 256 + k] = __float2bfloat16(Wx[k * 768 + n]);
}

// ---------------- K4: xg = relu(Ai[i]+Aj[j]) @ W_x + b_g  (bf16 MFMA) ----------------
__global__ __launch_bounds__(256) void k_gemm(const float* __restrict__ Ai,
    const float* __restrict__ Aj, const __hip_bfloat16* __restrict__ WxT,
    const float* __restrict__ bg, __hip_bfloat16* __restrict__ xg) {
  __shared__ alignas(128) char smem[32768];  // A tile 16KB | B tile 16KB
  char* const smA = smem;
  char* const smB = smem + 16384;
  const int t = threadIdx.x;
  const int lane = t & 63, w = t >> 6;
  const int wr = w >> 1, wc = w & 1;
  const int m0 = blockIdx.x * 128;
  const int n0 = blockIdx.y * 128;
  const char* const Wb = (const char*)WxT;

  const int b = m0 >> 12;
  const int ibase = (m0 >> 6) & 63;
  const int rr = t >> 1, half = t & 1;
  const int jj_ = rr & 63, ii_ = ibase + (rr >> 6);
  const float* const aiRow = Ai + ((size_t)b * 64 + ii_) * 256 + half * 32;
  const float* const ajRow = Aj + ((size_t)b * 64 + jj_) * 256 + half * 32;
  char* const dstA = smA + rr * 128 + half * 64;

  f32x4 acc[4][4];
  const f32x4 zero = {0.f, 0.f, 0.f, 0.f};
  #pragma unroll
  for (int a2 = 0; a2 < 4; ++a2)
    #pragma unroll
    for (int b2 = 0; b2 < 4; ++b2) acc[a2][b2] = zero;

  for (int s = 0; s < 4; ++s) {   // K-steps of 64 (K=256)
    const int k0 = s * 64;
    #pragma unroll
    for (int q = 0; q < 4; ++q) {
      const float4 a0 = *(const float4*)(aiRow + k0 + q * 8);
      const float4 a1 = *(const float4*)(aiRow + k0 + q * 8 + 4);
      const float4 c0 = *(const float4*)(ajRow + k0 + q * 8);
      const float4 c1 = *(const float4*)(ajRow + k0 + q * 8 + 4);
      bf16x8 v;
      v[0] = bfc(fmaxf(a0.x + c0.x, 0.f)); v[1] = bfc(fmaxf(a0.y + c0.y, 0.f));
      v[2] = bfc(fmaxf(a0.z + c0.z, 0.f)); v[3] = bfc(fmaxf(a0.w + c0.w, 0.f));
      v[4] = bfc(fmaxf(a1.x + c1.x, 0.f)); v[5] = bfc(fmaxf(a1.y + c1.y, 0.f));
      v[6] = bfc(fmaxf(a1.z + c1.z, 0.f)); v[7] = bfc(fmaxf(a1.w + c1.w, 0.f));
      *(bf16x8*)(dstA + q * 16) = v;
    }
    #pragma unroll
    for (int q = 0; q < 4; ++q) {
      const int chunk = w * 4 + q;
      const int tt2 = chunk * 1024 + lane * 16;
      const int row = tt2 >> 7;
      const int kb = tt2 & 0x7f;
      __builtin_amdgcn_global_load_lds(
          (as1c_t*)(Wb + (size_t)(n0 + row) * 512 + s * 128 + kb),
          (as3_t*)(smB + chunk * 1024), 16, 0, 0);
    }
    __syncthreads();
    #pragma unroll
    for (int kk = 0; kk < 2; ++kk) {
      bf16x8 af[4], bfr[4];
      const int kloc = kk * 64 + ((lane >> 4) << 4);
      #pragma unroll
      for (int ft = 0; ft < 4; ++ft) {
        const int rowa = wr * 64 + ft * 16 + (lane & 15);
        af[ft] = *(const bf16x8*)(smA + rowa * 128 + kloc);
      }
      #pragma unroll
      for (int fn = 0; fn < 4; ++fn) {
        const int rowb = wc * 64 + fn * 16 + (lane & 15);
        bfr[fn] = *(const bf16x8*)(smB + rowb * 128 + kloc);
      }
      #pragma unroll
      for (int ft = 0; ft < 4; ++ft)
        #pragma unroll
        for (int fn = 0; fn < 4; ++fn)
          acc[ft][fn] = __builtin_amdgcn_mfma_f32_16x16x32_bf16(
              af[ft], bfr[fn], acc[ft][fn], 0, 0, 0);
    }
    __syncthreads();
  }

  #pragma unroll
  for (int ft = 0; ft < 4; ++ft) {
    const int mbase = m0 + wr * 64 + ft * 16 + ((lane >> 4) << 2);
    #pragma unroll
    for (int fn = 0; fn < 4; ++fn) {
      const int n = n0 + wc * 64 + fn * 16 + (lane & 15);
      const float bias = bg[n];
      #pragma unroll
      for (int jj = 0; jj < 4; ++jj)
        xg[(size_t)(mbase + jj) * 768 + n] = __float2bfloat16(acc[ft][fn][jj] + bias);
    }
  }
}

// ---------------- K5: persistent wavefront 2-D GRU recurrence ----------------
// grid 256 = (row i)*4 + batch-group bg; block 256 (one thread per H-column).
// Row dependency via ring buffer (depth 2) + agent-scope flags; left state in regs.
__global__ __launch_bounds__(256) void k_wave(const __hip_bfloat16* __restrict__ xg,
    const float* __restrict__ Uzr, const float* __restrict__ Ush,
    const float* __restrict__ Wt, const float* __restrict__ bt,
    const int* __restrict__ ym,
    float* __restrict__ couples, float* __restrict__ diagbuf,
    float* __restrict__ ring, int* __restrict__ prod, int* __restrict__ cons) {
  __shared__ float sp[256][8];
  __shared__ float rs[256][8];
  __shared__ float red[4][16];
  const int t = threadIdx.x;
  const int c = t;
  const int bx = blockIdx.x;
  const int i = bx >> 2, bg = bx & 3;
  const int b0 = bg * 8;

  int* const pprev = prod + ((i - 1) * 4 + bg);      // valid if i>0
  int* const pcons_self = cons + (i * 4 + bg);
  int* const pcons_next = cons + ((i + 1) * 4 + bg); // valid if i<63
  int* const pprod_self = prod + (i * 4 + bg);
  const float* const ring_rd = ring + (size_t)((i - 1) * 4 + bg) * 2 * 2048;
  float* const ring_wr = ring + (size_t)(i * 4 + bg) * 2 * 2048;

  float sl[8];
  #pragma unroll
  for (int bb = 0; bb < 8; ++bb) sl[bb] = 0.f;
  int mi[8];
  #pragma unroll
  for (int bb = 0; bb < 8; ++bb) mi[bb] = ym[(b0 + bb) * 64 + i];

  for (int j = 0; j < 64; ++j) {
    // ---- phase 0: wait for up-neighbor, build s_prev in LDS [k][bb] ----
    float su[8];
    if (i > 0) {
      while (__hip_atomic_load(pprev, __ATOMIC_RELAXED, __HIP_MEMORY_SCOPE_AGENT) < j + 1)
        __builtin_amdgcn_s_sleep(2);
      __threadfence();
      const float* src = ring_rd + (j & 1) * 2048 + c * 8;
      const float4 u0 = *(const float4*)(src);
      const float4 u1 = *(const float4*)(src + 4);
      su[0] = u0.x; su[1] = u0.y; su[2] = u0.z; su[3] = u0.w;
      su[4] = u1.x; su[5] = u1.y; su[6] = u1.z; su[7] = u1.w;
    } else {
      #pragma unroll
      for (int bb = 0; bb < 8; ++bb) su[bb] = 0.f;
    }
    #pragma unroll
    for (int bb = 0; bb < 8; ++bb) sp[c][bb] = 0.5f * (sl[bb] + su[bb]);
    __syncthreads();
    if (i > 0 && t == 0)
      __hip_atomic_store(pcons_self, j + 1, __ATOMIC_RELAXED, __HIP_MEMORY_SCOPE_AGENT);

    // ---- phase 1: z,r = sigmoid(xg[:512] + s_prev @ Us_zr) ----
    float accz[8], accr[8];
    #pragma unroll
    for (int bb = 0; bb < 8; ++bb) {
      const size_t xrow = ((size_t)(b0 + bb) * 4096 + (size_t)i * 64 + j) * 768;
      accz[bb] = __bfloat162float(xg[xrow + c]);
      accr[bb] = __bfloat162float(xg[xrow + 256 + c]);
    }
    for (int k = 0; k < 256; ++k) {
      const float w0 = Uzr[k * 512 + c];
      const float w1 = Uzr[k * 512 + 256 + c];
      const float4 s0 = *(const float4*)&sp[k][0];
      const float4 s1 = *(const float4*)&sp[k][4];
      accz[0] = fmaf(s0.x, w0, accz[0]); accr[0] = fmaf(s0.x, w1, accr[0]);
      accz[1] = fmaf(s0.y, w0, accz[1]); accr[1] = fmaf(s0.y, w1, accr[1]);
      accz[2] = fmaf(s0.z, w0, accz[2]); accr[2] = fmaf(s0.z, w1, accr[2]);
      accz[3] = fmaf(s0.w, w0, accz[3]); accr[3] = fmaf(s0.w, w1, accr[3]);
      accz[4] = fmaf(s1.x, w0, accz[4]); accr[4] = fmaf(s1.x, w1, accr[4]);
      accz[5] = fmaf(s1.y, w0, accz[5]); accr[5] = fmaf(s1.y, w1, accr[5]);
      accz[6] = fmaf(s1.z, w0, accz[6]); accr[6] = fmaf(s1.z, w1, accr[6]);
      accz[7] = fmaf(s1.w, w0, accz[7]); accr[7] = fmaf(s1.w, w1, accr[7]);
    }
    float zv[8];
    #pragma unroll
    for (int bb = 0; bb < 8; ++bb) {
      zv[bb] = sigmoidf_(accz[bb]);
      const float rr = sigmoidf_(accr[bb]);
      rs[c][bb] = rr * sp[c][bb];
    }
    __syncthreads();

    // ---- phase 2: h = tanh(xg[512:] + (r*s_prev) @ Us_h); state update ----
    float acch[8];
    #pragma unroll
    for (int bb = 0; bb < 8; ++bb) {
      const size_t xrow = ((size_t)(b0 + bb) * 4096 + (size_t)i * 64 + j) * 768;
      acch[bb] = __bfloat162float(xg[xrow + 512 + c]);
    }
    for (int k = 0; k < 256; ++k) {
      const float w = Ush[k * 256 + c];
      const float4 r0 = *(const float4*)&rs[k][0];
      const float4 r1 = *(const float4*)&rs[k][4];
      acch[0] = fmaf(r0.x, w, acch[0]); acch[1] = fmaf(r0.y, w, acch[1]);
      acch[2] = fmaf(r0.z, w, acch[2]); acch[3] = fmaf(r0.w, w, acch[3]);
      acch[4] = fmaf(r1.x, w, acch[4]); acch[5] = fmaf(r1.y, w, acch[5]);
      acch[6] = fmaf(r1.z, w, acch[6]); acch[7] = fmaf(r1.w, w, acch[7]);
    }
    float cp[16];
    #pragma unroll
    for (int bb = 0; bb < 8; ++bb) {
      const float h = tanhf(acch[bb]);
      const float spv = sp[c][bb];
      float sv = (1.f - zv[bb]) * spv + zv[bb] * h;
      sv *= (float)(mi[bb] & ym[(b0 + bb) * 64 + j]);
      sl[bb] = sv;
      if (i == j) diagbuf[((size_t)((b0 + bb) * 64 + i)) * 256 + c] = sv;
      cp[bb * 2 + 0] = sv * Wt[c * 2 + 0];
      cp[bb * 2 + 1] = sv * Wt[c * 2 + 1];
    }

    // ---- publish state to row i+1 (ring, credit-gated) ----
    if (i < 63) {
      while (__hip_atomic_load(pcons_next, __ATOMIC_RELAXED, __HIP_MEMORY_SCOPE_AGENT) < j - 1)
        __builtin_amdgcn_s_sleep(2);
      float* dst = ring_wr + (j & 1) * 2048 + c * 8;
      float4 v0, v1;
      v0.x = sl[0]; v0.y = sl[1]; v0.z = sl[2]; v0.w = sl[3];
      v1.x = sl[4]; v1.y = sl[5]; v1.z = sl[6]; v1.w = sl[7];
      *(float4*)(dst) = v0;
      *(float4*)(dst + 4) = v1;
    }

    // ---- fused couples projection (block reduce over c) ----
    #pragma unroll
    for (int v = 0; v < 16; ++v) {
      float x = cp[v];
      x += __shfl_xor(x, 1);  x += __shfl_xor(x, 2);  x += __shfl_xor(x, 4);
      x += __shfl_xor(x, 8);  x += __shfl_xor(x, 16); x += __shfl_xor(x, 32);
      cp[v] = x;
    }
    if ((t & 63) == 0) {
      #pragma unroll
      for (int v = 0; v < 16; ++v) red[t >> 6][v] = cp[v];
    }
    __threadfence();
    __syncthreads();
    if (i < 63 && t == 0)
      __hip_atomic_store(pprod_self, j + 1, __ATOMIC_RELAXED, __HIP_MEMORY_SCOPE_AGENT);
    if (t < 16) {
      const float x = red[0][t] + red[1][t] + red[2][t] + red[3][t];
      const int bb = t >> 1, o = t & 1;
      couples[(((size_t)(b0 + bb) * 4096) + (size_t)i * 64 + j) * 2 + o] = x + bt[o];
    }
  }
}

// ---------------- K6: pred_e / pred_c from diagonal states ----------------
__global__ __launch_bounds__(256) void k_head(const float* __restrict__ diagbuf,
    const float* __restrict__ We, const float* __restrict__ be,
    const float* __restrict__ Wc, const float* __restrict__ bc,
    float* __restrict__ pe, float* __restrict__ pc) {
  __shared__ float red[4][4];
  const int bn = blockIdx.x;
  const int t = threadIdx.x;
  const float s = diagbuf[(size_t)bn * 256 + t];
  float v[4] = { s * We[t * 2], s * We[t * 2 + 1], s * Wc[t * 2], s * Wc[t * 2 + 1] };
  #pragma unroll
  for (int q = 0; q < 4; ++q) {
    float x = v[q];
    x += __shfl_xor(x, 1);  x += __shfl_xor(x, 2);  x += __shfl_xor(x, 4);
    x += __shfl_xor(x, 8);  x += __shfl_xor(x, 16); x += __shfl_xor(x, 32);
    v[q] = x;
  }
  if ((t & 63) == 0) {
    #pragma unroll
    for (int q = 0; q < 4; ++q) red[t >> 6][q] = v[q];
  }
  __syncthreads();
  if (t < 4) {
    const float x = red[0][t] + red[1][t] + red[2][t] + red[3][t];
    if (t < 2) pe[bn * 2 + t] = x + be[t];
    else       pc[bn * 2 + (t - 2)] = x + bc[t - 2];
  }
}

extern "C" void kernel_launch(void* const* d_in, const int* in_sizes, int n_in,
                              void* d_out, int out_size, void* d_ws, size_t ws_size,
                              hipStream_t stream) {
  const float* hidden = (const float*)d_in[0];
  const float* Wred = (const float*)d_in[1];
  const float* bred = (const float*)d_in[2];
  const float* Wcat = (const float*)d_in[3];
  const float* bcat = (const float*)d_in[4];
  const float* Wx   = (const float*)d_in[5];
  const float* Uzr  = (const float*)d_in[6];
  const float* Ush  = (const float*)d_in[7];
  const float* bg   = (const float*)d_in[8];
  const float* We   = (const float*)d_in[9];
  const float* be   = (const float*)d_in[10];
  const float* Wc   = (const float*)d_in[11];
  const float* bc   = (const float*)d_in[12];
  const float* Wt   = (const float*)d_in[13];
  const float* bt   = (const float*)d_in[14];
  const int* cidx   = (const int*)d_in[15];
  const int* ym     = (const int*)d_in[16];

  // ---- workspace layout (total 214,302,720 B — same as proven round-2 size) ----
  char* ws = (char*)d_ws;
  const size_t MB2 = 2097152;
  float* r    = (float*)(ws);                          // 2 MB
  float* Ai   = (float*)(ws + 1 * MB2);                // 2 MB
  float* Aj   = (float*)(ws + 2 * MB2);                // 2 MB
  float* diag = (float*)(ws + 3 * MB2);                // 2 MB
  __hip_bfloat16* WxT = (__hip_bfloat16*)(ws + 4 * MB2);   // 393,216 B
  char* flags = ws + 4 * MB2 + 393216;                 // 65,536 B (prod 1KB | cons 1KB)
  int* prod = (int*)flags;
  int* cons = (int*)(flags + 1024);
  float* ring = (float*)(ws + 4 * MB2 + 393216 + 65536);   // 63*4*2*2048*4 = 4,128,768 B
  __hip_bfloat16* xg = (__hip_bfloat16*)(ws + 12976128 - 2 * MB2); // 10,878,912? no:
  // recompute: base = 4*MB2 + 393216 + 65536 + 4128768 = 8388608+393216+65536+4128768
  xg = (__hip_bfloat16*)(ws + (4 * MB2 + 393216 + 65536 + 4128768));

  float* couples = (float*)d_out;          // (32,64,64,2)
  float* pe = couples + 262144;            // (32,64,2)
  float* pc = couples + 266240;            // (32,64,2)

  hipMemsetAsync(flags, 0, 2048, stream);

  k_r<<<256, 256, 0, stream>>>(hidden, Wred, bred, cidx, r);
  k_ab<<<256, 256, 0, stream>>>(r, Wcat, bcat, Ai, Aj);
  k_wt<<<768, 256, 0, stream>>>(Wx, WxT);
  k_gemm<<<dim3(1024, 6), 256, 0, stream>>>(Ai, Aj, WxT, bg, xg);
  k_wave<<<256, 256, 0, stream>>>(xg, Uzr, Ush, Wt, bt, ym,
                                  couples, diag, ring, prod, cons);
  k_head<<<2048, 256, 0, stream>>>(diag, We, be, Wc, bc, pe, pc);
}

// Round 4
// 4096.178 us; speedup vs baseline: 2.0183x; 2.0183x over previous
//
#include <hip/hip_runtime.h>
#include <hip/hip_bf16.h>

typedef float f32x4 __attribute__((ext_vector_type(4)));
typedef __bf16 bf16x8 __attribute__((ext_vector_type(8)));
typedef __bf16 bf16x4 __attribute__((ext_vector_type(4)));

using as1c_t = __attribute__((address_space(1))) const char;
using as3_t  = __attribute__((address_space(3))) char;

static __device__ __forceinline__ float sigmoidf_(float x) {
  return 1.f / (1.f + __expf(-x));
}
static __device__ __forceinline__ float tanhf_(float x) {
  return 1.f - 2.f / (__expf(2.f * x) + 1.f);
}
static __device__ __forceinline__ __bf16 bfc(float x) { return (__bf16)x; }
static __device__ __forceinline__ float bf2f_(unsigned short u) {
  return __uint_as_float(((unsigned)u) << 16);
}

// ---------------- K1: r = gather(hidden) @ W_red + b_red ----------------
__global__ __launch_bounds__(256) void k_r(const float* __restrict__ hidden,
    const float* __restrict__ Wred, const float* __restrict__ bred,
    const int* __restrict__ cidx, float* __restrict__ r) {
  __shared__ float docsT[768][8];
  const int bx = blockIdx.x;
  const int b = bx >> 3, n0 = (bx & 7) * 8;
  const int t = threadIdx.x;
  #pragma unroll
  for (int g = 0; g < 8; ++g) {
    const int tok = cidx[b * 64 + n0 + g];
    const float* src = hidden + ((size_t)b * 512 + tok) * 768;
    for (int f = t; f < 768; f += 256) docsT[f][g] = src[f];
  }
  __syncthreads();
  float acc[8];
  #pragma unroll
  for (int g = 0; g < 8; ++g) acc[g] = bred[t];
  for (int f = 0; f < 768; ++f) {
    const float w = Wred[f * 256 + t];
    const float4 d0 = *(const float4*)&docsT[f][0];
    const float4 d1 = *(const float4*)&docsT[f][4];
    acc[0] = fmaf(d0.x, w, acc[0]); acc[1] = fmaf(d0.y, w, acc[1]);
    acc[2] = fmaf(d0.z, w, acc[2]); acc[3] = fmaf(d0.w, w, acc[3]);
    acc[4] = fmaf(d1.x, w, acc[4]); acc[5] = fmaf(d1.y, w, acc[5]);
    acc[6] = fmaf(d1.z, w, acc[6]); acc[7] = fmaf(d1.w, w, acc[7]);
  }
  #pragma unroll
  for (int g = 0; g < 8; ++g) r[((size_t)(b * 64 + n0 + g)) * 256 + t] = acc[g];
}

// ---------------- K2: Ai = r@Wcat[:256] + b_cat ; Aj = r@Wcat[256:] ----------------
__global__ __launch_bounds__(256) void k_ab(const float* __restrict__ r,
    const float* __restrict__ Wcat, const float* __restrict__ bcat,
    float* __restrict__ Ai, float* __restrict__ Aj) {
  __shared__ float rT[256][8];
  const int bx = blockIdx.x;
  const int b = bx >> 3, n0 = (bx & 7) * 8;
  const int t = threadIdx.x;
  #pragma unroll
  for (int g = 0; g < 8; ++g)
    rT[t][g] = r[((size_t)(b * 64 + n0 + g)) * 256 + t];
  __syncthreads();
  float ai[8], aj[8];
  #pragma unroll
  for (int g = 0; g < 8; ++g) { ai[g] = bcat[t]; aj[g] = 0.f; }
  for (int k = 0; k < 256; ++k) {
    const float w0 = Wcat[k * 256 + t];
    const float w1 = Wcat[(256 + k) * 256 + t];
    const float4 d0 = *(const float4*)&rT[k][0];
    const float4 d1 = *(const float4*)&rT[k][4];
    ai[0] = fmaf(d0.x, w0, ai[0]); aj[0] = fmaf(d0.x, w1, aj[0]);
    ai[1] = fmaf(d0.y, w0, ai[1]); aj[1] = fmaf(d0.y, w1, aj[1]);
    ai[2] = fmaf(d0.z, w0, ai[2]); aj[2] = fmaf(d0.z, w1, aj[2]);
    ai[3] = fmaf(d0.w, w0, ai[3]); aj[3] = fmaf(d0.w, w1, aj[3]);
    ai[4] = fmaf(d1.x, w0, ai[4]); aj[4] = fmaf(d1.x, w1, aj[4]);
    ai[5] = fmaf(d1.y, w0, ai[5]); aj[5] = fmaf(d1.y, w1, aj[5]);
    ai[6] = fmaf(d1.z, w0, ai[6]); aj[6] = fmaf(d1.z, w1, aj[6]);
    ai[7] = fmaf(d1.w, w0, ai[7]); aj[7] = fmaf(d1.w, w1, aj[7]);
  }
  #pragma unroll
  for (int g = 0; g < 8; ++g) {
    Ai[((size_t)(b * 64 + n0 + g)) * 256 + t] = ai[g];
    Aj[((size_t)(b * 64 + n0 + g)) * 256 + t] = aj[g];
  }
}

// ---------------- K3: weight transposes to bf16 ----------------
__global__ __launch_bounds__(256) void k_wt(const float* __restrict__ Wx,
                                            __hip_bfloat16* __restrict__ WxT) {
  const int n = blockIdx.x, k = threadIdx.x;
  WxT[n * 256 + k] = __float2bfloat16(Wx[k * 768 + n]);
}
__global__ __launch_bounds__(256) void k_tzr(const float* __restrict__ U,
                                             __hip_bfloat16* __restrict__ UT) {
  const int n = blockIdx.x, k = threadIdx.x;   // U[256][512] -> UT[512][256]
  UT[n * 256 + k] = __float2bfloat16(U[k * 512 + n]);
}
__global__ __launch_bounds__(256) void k_tsh(const float* __restrict__ U,
                                             __hip_bfloat16* __restrict__ UT) {
  const int n = blockIdx.x, k = threadIdx.x;   // U[256][256] -> UT[256][256]
  UT[n * 256 + k] = __float2bfloat16(U[k * 256 + n]);
}

// ---------------- K4: xg = relu(Ai[i]+Aj[j]) @ W_x + b_g  (bf16 MFMA) ----------------
__global__ __launch_bounds__(256) void k_gemm(const float* __restrict__ Ai,
    const float* __restrict__ Aj, const __hip_bfloat16* __restrict__ WxT,
    const float* __restrict__ bg, __hip_bfloat16* __restrict__ xg) {
  __shared__ alignas(128) char smem[32768];  // A tile 16KB | B tile 16KB
  char* const smA = smem;
  char* const smB = smem + 16384;
  const int t = threadIdx.x;
  const int lane = t & 63, w = t >> 6;
  const int wr = w >> 1, wc = w & 1;
  const int m0 = blockIdx.x * 128;
  const int n0 = blockIdx.y * 128;
  const char* const Wb = (const char*)WxT;

  const int b = m0 >> 12;
  const int ibase = (m0 >> 6) & 63;
  const int sRow4 = t >> 4;        // 0..15
  const int sK = (t & 15) * 4;     // float offset within 64-float k-chunk

  f32x4 acc[4][4];
  const f32x4 zero = {0.f, 0.f, 0.f, 0.f};
  #pragma unroll
  for (int a2 = 0; a2 < 4; ++a2)
    #pragma unroll
    for (int b2 = 0; b2 < 4; ++b2) acc[a2][b2] = zero;

  for (int s = 0; s < 4; ++s) {   // K-steps of 64 (K=256)
    const int k0 = s * 64;
    // A tile: coalesced (16 lanes cover one row's 256B), 8 passes of 16 rows
    #pragma unroll
    for (int p = 0; p < 8; ++p) {
      const int row = p * 16 + sRow4;
      const int ii2 = ibase + (row >> 6);
      const int jj2 = row & 63;
      const float4 av = *(const float4*)(Ai + ((size_t)b * 64 + ii2) * 256 + k0 + sK);
      const float4 cv = *(const float4*)(Aj + ((size_t)b * 64 + jj2) * 256 + k0 + sK);
      bf16x4 v;
      v[0] = bfc(fmaxf(av.x + cv.x, 0.f)); v[1] = bfc(fmaxf(av.y + cv.y, 0.f));
      v[2] = bfc(fmaxf(av.z + cv.z, 0.f)); v[3] = bfc(fmaxf(av.w + cv.w, 0.f));
      *(bf16x4*)(smA + row * 128 + (t & 15) * 8) = v;
    }
    // B tile via async global->LDS
    #pragma unroll
    for (int q = 0; q < 4; ++q) {
      const int chunk = w * 4 + q;
      const int tt2 = chunk * 1024 + lane * 16;
      const int row = tt2 >> 7;
      const int kb = tt2 & 0x7f;
      __builtin_amdgcn_global_load_lds(
          (as1c_t*)(Wb + (size_t)(n0 + row) * 512 + s * 128 + kb),
          (as3_t*)(smB + chunk * 1024), 16, 0, 0);
    }
    __syncthreads();
    #pragma unroll
    for (int kk = 0; kk < 2; ++kk) {
      bf16x8 af[4], bfr[4];
      const int kloc = kk * 64 + ((lane >> 4) << 4);
      #pragma unroll
      for (int ft = 0; ft < 4; ++ft) {
        const int rowa = wr * 64 + ft * 16 + (lane & 15);
        af[ft] = *(const bf16x8*)(smA + rowa * 128 + kloc);
      }
      #pragma unroll
      for (int fn = 0; fn < 4; ++fn) {
        const int rowb = wc * 64 + fn * 16 + (lane & 15);
        bfr[fn] = *(const bf16x8*)(smB + rowb * 128 + kloc);
      }
      #pragma unroll
      for (int ft = 0; ft < 4; ++ft)
        #pragma unroll
        for (int fn = 0; fn < 4; ++fn)
          acc[ft][fn] = __builtin_amdgcn_mfma_f32_16x16x32_bf16(
              af[ft], bfr[fn], acc[ft][fn], 0, 0, 0);
    }
    __syncthreads();
  }

  // epilogue: bounce through LDS for 64B-contiguous stores
  __hip_bfloat16* smC = (__hip_bfloat16*)smem;   // [128][128] bf16 = 32KB
  #pragma unroll
  for (int ft = 0; ft < 4; ++ft) {
    #pragma unroll
    for (int fn = 0; fn < 4; ++fn) {
      const int nl = wc * 64 + fn * 16 + (lane & 15);
      const float bias = bg[n0 + nl];
      #pragma unroll
      for (int jj = 0; jj < 4; ++jj) {
        const int ml = wr * 64 + ft * 16 + ((lane >> 4) << 2) + jj;
        smC[ml * 128 + nl] = __float2bfloat16(acc[ft][fn][jj] + bias);
      }
    }
  }
  __syncthreads();
  #pragma unroll
  for (int pp = 0; pp < 2; ++pp) {
    const int row = pp * 64 + (t >> 2);
    const int qtr = t & 3;
    #pragma unroll
    for (int q2 = 0; q2 < 4; ++q2) {
      const f32x4 v = *(const f32x4*)((const char*)smC + row * 256 + qtr * 64 + q2 * 16);
      *(f32x4*)((char*)xg + ((size_t)(m0 + row) * 768 + n0) * 2 + qtr * 64 + q2 * 16) = v;
    }
  }
}

// ---------------- K5: persistent MFMA wavefront 2-D GRU ----------------
// grid 64 (one block per row i), block 512 (8 waves; wave w owns cols [32w,32w+32))
__global__ __launch_bounds__(512, 2) void k_wave2(
    const __hip_bfloat16* __restrict__ xg_,
    const __hip_bfloat16* __restrict__ UzT_,
    const __hip_bfloat16* __restrict__ UhT_,
    const float* __restrict__ Wt, const float* __restrict__ bt,
    const int* __restrict__ ym,
    float* __restrict__ couples, float* __restrict__ diagbuf,
    float* __restrict__ ring, int* __restrict__ prod, int* __restrict__ cons) {
  __shared__ float sL[32][264];     // s_left (f32)
  __shared__ float spf[32][264];    // s_prev (f32)
  __shared__ __bf16 sph[32][264];   // s_prev hi
  __shared__ __bf16 spl[32][264];   // s_prev lo
  __shared__ __bf16 rsh[32][264];   // r*s_prev (bf16)
  __shared__ float red[32][2];

  const __bf16* UzT = (const __bf16*)UzT_;
  const __bf16* UhT = (const __bf16*)UhT_;
  const unsigned short* xg = (const unsigned short*)xg_;
  const int t = threadIdx.x;
  const int i = blockIdx.x;
  const int wv = t >> 6, ln = t & 63;
  const int l15 = ln & 15, l4 = ln >> 4;
  const int cbase = wv * 32;

  for (int q = t; q < 32 * 264; q += 512) (&sL[0][0])[q] = 0.f;
  if (t < 64) red[t >> 1][t & 1] = 0.f;

  const int m0ph = t >> 4;           // phase-0 row (0..31)
  const int c0l = (t & 15) * 2;      // phase-0 col-pair base within 32-chunk
  int mrow[8]; int ymi_[8];
  const unsigned short* xgm[8];
  #pragma unroll
  for (int mt = 0; mt < 2; ++mt)
    #pragma unroll
    for (int jj = 0; jj < 4; ++jj) {
      const int idx = mt * 4 + jj;
      const int m = mt * 16 + l4 * 4 + jj;
      mrow[idx] = m;
      ymi_[idx] = ym[m * 64 + i];
      xgm[idx] = xg + ((size_t)m * 4096 + (size_t)i * 64) * 768;
    }
  float wtv[2][2];
  #pragma unroll
  for (int ntl = 0; ntl < 2; ++ntl) {
    const int cc2 = cbase + ntl * 16 + l15;
    wtv[ntl][0] = Wt[cc2 * 2 + 0]; wtv[ntl][1] = Wt[cc2 * 2 + 1];
  }
  const float* ring_rd = ring + (size_t)(i - 1) * 16384;
  float* ring_wr = ring + (size_t)i * 16384;
  const f32x4 z4 = {0.f, 0.f, 0.f, 0.f};
  __syncthreads();

  for (int j = 0; j < 64; ++j) {
    // xg preloads (issued early; consumed after matmuls)
    float xzf[16], xrf[16], xhf[16];
    #pragma unroll
    for (int idx = 0; idx < 8; ++idx) {
      const unsigned short* px = xgm[idx] + (size_t)j * 768;
      #pragma unroll
      for (int ntl = 0; ntl < 2; ++ntl) {
        const int cc2 = cbase + ntl * 16 + l15;
        xzf[idx * 2 + ntl] = bf2f_(px[cc2]);
        xrf[idx * 2 + ntl] = bf2f_(px[cc2 + 256]);
        xhf[idx * 2 + ntl] = bf2f_(px[cc2 + 512]);
      }
    }

    // ---- phase 0: wait for up-row, build s_prev (f32 + hi/lo bf16) ----
    if (i > 0) {
      while (__hip_atomic_load(&prod[i - 1], __ATOMIC_RELAXED,
                               __HIP_MEMORY_SCOPE_AGENT) < j + 1)
        __builtin_amdgcn_s_sleep(4);
      __threadfence();
    }
    const float* rslot = ring_rd + (j & 1) * 8192;
    #pragma unroll
    for (int q = 0; q < 8; ++q) {
      const int c0 = q * 32 + c0l;
      float su0 = 0.f, su1 = 0.f;
      if (i > 0) {
        unsigned long long v = __hip_atomic_load(
            (unsigned long long*)(rslot + m0ph * 256 + c0),
            __ATOMIC_RELAXED, __HIP_MEMORY_SCOPE_AGENT);
        su0 = __uint_as_float((unsigned)v);
        su1 = __uint_as_float((unsigned)(v >> 32));
      }
      const float2 slv = *(const float2*)&sL[m0ph][c0];
      const float sp0 = 0.5f * (slv.x + su0), sp1 = 0.5f * (slv.y + su1);
      spf[m0ph][c0] = sp0; spf[m0ph][c0 + 1] = sp1;
      const __bf16 h0 = (__bf16)sp0, h1 = (__bf16)sp1;
      sph[m0ph][c0] = h0; sph[m0ph][c0 + 1] = h1;
      spl[m0ph][c0] = (__bf16)(sp0 - (float)h0);
      spl[m0ph][c0 + 1] = (__bf16)(sp1 - (float)h1);
    }
    __syncthreads();                                      // (b) sp ready
    if (i > 0 && t == 0)
      __hip_atomic_store(&cons[i], j + 1, __ATOMIC_RELAXED, __HIP_MEMORY_SCOPE_AGENT);

    // ---- zr matmul: [32,256]@[256,512] with hi/lo A-split ----
    f32x4 cz[2][2], cr[2][2];
    #pragma unroll
    for (int a2 = 0; a2 < 2; ++a2)
      #pragma unroll
      for (int b2 = 0; b2 < 2; ++b2) { cz[a2][b2] = z4; cr[a2][b2] = z4; }
    #pragma unroll
    for (int ks = 0; ks < 8; ++ks) {
      const int ab = ks * 64 + l4 * 16;
      const bf16x8 ah0 = *(const bf16x8*)((const char*)&sph[0][0] + (size_t)l15 * 528 + ab);
      const bf16x8 ah1 = *(const bf16x8*)((const char*)&sph[0][0] + (size_t)(16 + l15) * 528 + ab);
      const bf16x8 al0 = *(const bf16x8*)((const char*)&spl[0][0] + (size_t)l15 * 528 + ab);
      const bf16x8 al1 = *(const bf16x8*)((const char*)&spl[0][0] + (size_t)(16 + l15) * 528 + ab);
      const int ke = ks * 32 + l4 * 8;
      const bf16x8 bz0 = *(const bf16x8*)(UzT + (size_t)(cbase + l15) * 256 + ke);
      const bf16x8 bz1 = *(const bf16x8*)(UzT + (size_t)(cbase + 16 + l15) * 256 + ke);
      const bf16x8 br0 = *(const bf16x8*)(UzT + (size_t)(256 + cbase + l15) * 256 + ke);
      const bf16x8 br1 = *(const bf16x8*)(UzT + (size_t)(256 + cbase + 16 + l15) * 256 + ke);
      cz[0][0] = __builtin_amdgcn_mfma_f32_16x16x32_bf16(ah0, bz0, cz[0][0], 0, 0, 0);
      cz[0][0] = __builtin_amdgcn_mfma_f32_16x16x32_bf16(al0, bz0, cz[0][0], 0, 0, 0);
      cz[0][1] = __builtin_amdgcn_mfma_f32_16x16x32_bf16(ah0, bz1, cz[0][1], 0, 0, 0);
      cz[0][1] = __builtin_amdgcn_mfma_f32_16x16x32_bf16(al0, bz1, cz[0][1], 0, 0, 0);
      cz[1][0] = __builtin_amdgcn_mfma_f32_16x16x32_bf16(ah1, bz0, cz[1][0], 0, 0, 0);
      cz[1][0] = __builtin_amdgcn_mfma_f32_16x16x32_bf16(al1, bz0, cz[1][0], 0, 0, 0);
      cz[1][1] = __builtin_amdgcn_mfma_f32_16x16x32_bf16(ah1, bz1, cz[1][1], 0, 0, 0);
      cz[1][1] = __builtin_amdgcn_mfma_f32_16x16x32_bf16(al1, bz1, cz[1][1], 0, 0, 0);
      cr[0][0] = __builtin_amdgcn_mfma_f32_16x16x32_bf16(ah0, br0, cr[0][0], 0, 0, 0);
      cr[0][0] = __builtin_amdgcn_mfma_f32_16x16x32_bf16(al0, br0, cr[0][0], 0, 0, 0);
      cr[0][1] = __builtin_amdgcn_mfma_f32_16x16x32_bf16(ah0, br1, cr[0][1], 0, 0, 0);
      cr[0][1] = __builtin_amdgcn_mfma_f32_16x16x32_bf16(al0, br1, cr[0][1], 0, 0, 0);
      cr[1][0] = __builtin_amdgcn_mfma_f32_16x16x32_bf16(ah1, br0, cr[1][0], 0, 0, 0);
      cr[1][0] = __builtin_amdgcn_mfma_f32_16x16x32_bf16(al1, br0, cr[1][0], 0, 0, 0);
      cr[1][1] = __builtin_amdgcn_mfma_f32_16x16x32_bf16(ah1, br1, cr[1][1], 0, 0, 0);
      cr[1][1] = __builtin_amdgcn_mfma_f32_16x16x32_bf16(al1, br1, cr[1][1], 0, 0, 0);
    }

    // ---- gates + rs ----
    float zz[16];
    #pragma unroll
    for (int mt = 0; mt < 2; ++mt)
      #pragma unroll
      for (int ntl = 0; ntl < 2; ++ntl)
        #pragma unroll
        for (int jj = 0; jj < 4; ++jj) {
          const int fi = (mt * 4 + jj) * 2 + ntl;
          const int m = mt * 16 + l4 * 4 + jj;
          const int cc2 = cbase + ntl * 16 + l15;
          const float zv = sigmoidf_(cz[mt][ntl][jj] + xzf[fi]);
          const float rv = sigmoidf_(cr[mt][ntl][jj] + xrf[fi]);
          zz[fi] = zv;
          rsh[m][cc2] = (__bf16)(rv * spf[m][cc2]);
        }
    if (i < 63) {
      while (__hip_atomic_load(&cons[i + 1], __ATOMIC_RELAXED,
                               __HIP_MEMORY_SCOPE_AGENT) < j - 1)
        __builtin_amdgcn_s_sleep(4);
    }
    __syncthreads();                                      // (e) rs ready, ring slot free

    // ---- h matmul: [32,256]@[256,256] ----
    f32x4 ch[2][2];
    #pragma unroll
    for (int a2 = 0; a2 < 2; ++a2)
      #pragma unroll
      for (int b2 = 0; b2 < 2; ++b2) ch[a2][b2] = z4;
    #pragma unroll
    for (int ks = 0; ks < 8; ++ks) {
      const int ab = ks * 64 + l4 * 16;
      const bf16x8 a0 = *(const bf16x8*)((const char*)&rsh[0][0] + (size_t)l15 * 528 + ab);
      const bf16x8 a1 = *(const bf16x8*)((const char*)&rsh[0][0] + (size_t)(16 + l15) * 528 + ab);
      const int ke = ks * 32 + l4 * 8;
      const bf16x8 b0 = *(const bf16x8*)(UhT + (size_t)(cbase + l15) * 256 + ke);
      const bf16x8 b1 = *(const bf16x8*)(UhT + (size_t)(cbase + 16 + l15) * 256 + ke);
      ch[0][0] = __builtin_amdgcn_mfma_f32_16x16x32_bf16(a0, b0, ch[0][0], 0, 0, 0);
      ch[0][1] = __builtin_amdgcn_mfma_f32_16x16x32_bf16(a0, b1, ch[0][1], 0, 0, 0);
      ch[1][0] = __builtin_amdgcn_mfma_f32_16x16x32_bf16(a1, b0, ch[1][0], 0, 0, 0);
      ch[1][1] = __builtin_amdgcn_mfma_f32_16x16x32_bf16(a1, b1, ch[1][1], 0, 0, 0);
    }

    // ---- update + ring publish + couples ----
    int ymj_[8];
    #pragma unroll
    for (int idx = 0; idx < 8; ++idx) ymj_[idx] = ym[mrow[idx] * 64 + j];
    float* wslot = ring_wr + (j & 1) * 8192;
    float cp[2][4][2];
    #pragma unroll
    for (int mt = 0; mt < 2; ++mt)
      #pragma unroll
      for (int jj = 0; jj < 4; ++jj) { cp[mt][jj][0] = 0.f; cp[mt][jj][1] = 0.f; }
    #pragma unroll
    for (int mt = 0; mt < 2; ++mt)
      #pragma unroll
      for (int ntl = 0; ntl < 2; ++ntl)
        #pragma unroll
        for (int jj = 0; jj < 4; ++jj) {
          const int fi = (mt * 4 + jj) * 2 + ntl;
          const int m = mt * 16 + l4 * 4 + jj;
          const int cc2 = cbase + ntl * 16 + l15;
          const float hv = tanhf_(ch[mt][ntl][jj] + xhf[fi]);
          const float spv = spf[m][cc2];
          float sv = spv + zz[fi] * (hv - spv);
          sv *= (float)(ymi_[mt * 4 + jj] & ymj_[mt * 4 + jj]);
          sL[m][cc2] = sv;
          if (i < 63)
            __hip_atomic_store(wslot + m * 256 + cc2, sv,
                               __ATOMIC_RELAXED, __HIP_MEMORY_SCOPE_AGENT);
          if (j == i) diagbuf[((size_t)m * 64 + i) * 256 + cc2] = sv;
          cp[mt][jj][0] = fmaf(sv, wtv[ntl][0], cp[mt][jj][0]);
          cp[mt][jj][1] = fmaf(sv, wtv[ntl][1], cp[mt][jj][1]);
        }
    #pragma unroll
    for (int mt = 0; mt < 2; ++mt)
      #pragma unroll
      for (int jj = 0; jj < 4; ++jj)
        #pragma unroll
        for (int o = 0; o < 2; ++o) {
          float x = cp[mt][jj][o];
          x += __shfl_xor(x, 1); x += __shfl_xor(x, 2);
          x += __shfl_xor(x, 4); x += __shfl_xor(x, 8);
          cp[mt][jj][o] = x;
        }
    if (l15 == 0) {
      #pragma unroll
      for (int mt = 0; mt < 2; ++mt)
        #pragma unroll
        for (int jj = 0; jj < 4; ++jj) {
          const int m = mt * 16 + l4 * 4 + jj;
          atomicAdd(&red[m][0], cp[mt][jj][0]);
          atomicAdd(&red[m][1], cp[mt][jj][1]);
        }
    }
    __syncthreads();                                      // (h) cell done
    if (t < 64) {
      const int m = t >> 1, o = t & 1;
      couples[((size_t)m * 4096 + (size_t)i * 64 + j) * 2 + o] = red[m][o] + bt[o];
      red[m][o] = 0.f;
    }
    if (i < 63 && t == 0) {
      __threadfence();
      __hip_atomic_store(&prod[i], j + 1, __ATOMIC_RELAXED, __HIP_MEMORY_SCOPE_AGENT);
    }
  }
}

// ---------------- K6: pred_e / pred_c from diagonal states ----------------
__global__ __launch_bounds__(256) void k_head(const float* __restrict__ diagbuf,
    const float* __restrict__ We, const float* __restrict__ be,
    const float* __restrict__ Wc, const float* __restrict__ bc,
    float* __restrict__ pe, float* __restrict__ pc) {
  __shared__ float red[4][4];
  const int bn = blockIdx.x;
  const int t = threadIdx.x;
  const float s = diagbuf[(size_t)bn * 256 + t];
  float v[4] = { s * We[t * 2], s * We[t * 2 + 1], s * Wc[t * 2], s * Wc[t * 2 + 1] };
  #pragma unroll
  for (int q = 0; q < 4; ++q) {
    float x = v[q];
    x += __shfl_xor(x, 1);  x += __shfl_xor(x, 2);  x += __shfl_xor(x, 4);
    x += __shfl_xor(x, 8);  x += __shfl_xor(x, 16); x += __shfl_xor(x, 32);
    v[q] = x;
  }
  if ((t & 63) == 0) {
    #pragma unroll
    for (int q = 0; q < 4; ++q) red[t >> 6][q] = v[q];
  }
  __syncthreads();
  if (t < 4) {
    const float x = red[0][t] + red[1][t] + red[2][t] + red[3][t];
    if (t < 2) pe[bn * 2 + t] = x + be[t];
    else       pc[bn * 2 + (t - 2)] = x + bc[t - 2];
  }
}

extern "C" void kernel_launch(void* const* d_in, const int* in_sizes, int n_in,
                              void* d_out, int out_size, void* d_ws, size_t ws_size,
                              hipStream_t stream) {
  const float* hidden = (const float*)d_in[0];
  const float* Wred = (const float*)d_in[1];
  const float* bred = (const float*)d_in[2];
  const float* Wcat = (const float*)d_in[3];
  const float* bcat = (const float*)d_in[4];
  const float* Wx   = (const float*)d_in[5];
  const float* Uzr  = (const float*)d_in[6];
  const float* Ush  = (const float*)d_in[7];
  const float* bg   = (const float*)d_in[8];
  const float* We   = (const float*)d_in[9];
  const float* be   = (const float*)d_in[10];
  const float* Wc   = (const float*)d_in[11];
  const float* bc   = (const float*)d_in[12];
  const float* Wt   = (const float*)d_in[13];
  const float* bt   = (const float*)d_in[14];
  const int* cidx   = (const int*)d_in[15];
  const int* ym     = (const int*)d_in[16];

  // ---- workspace layout (max used: 212,602,880 B < proven 214,302,720) ----
  char* ws = (char*)d_ws;
  float* Ai   = (float*)(ws);                          // 2 MB
  float* Aj   = (float*)(ws + 2097152);                // 2 MB
  float* diag = (float*)(ws + 4194304);                // 2 MB
  __hip_bfloat16* WxT  = (__hip_bfloat16*)(ws + 6291456);   // 393,216
  __hip_bfloat16* UzrT = (__hip_bfloat16*)(ws + 6684672);   // 262,144
  __hip_bfloat16* UshT = (__hip_bfloat16*)(ws + 6946816);   // 131,072
  int* prod = (int*)(ws + 7077888);                    // flags: 4 KB
  int* cons = (int*)(ws + 7077888 + 1024);
  float* ring = (float*)(ws + 7081984);                // 64*2*32KB = 4 MB
  float* r = ring;                                     // alias: r dead before k_wave2
  __hip_bfloat16* xg = (__hip_bfloat16*)(ws + 11276288);    // 192 MiB

  float* couples = (float*)d_out;          // (32,64,64,2)
  float* pe = couples + 262144;            // (32,64,2)
  float* pc = couples + 266240;            // (32,64,2)

  hipMemsetAsync(ws + 7077888, 0, 4096, stream);
  k_r<<<256, 256, 0, stream>>>(hidden, Wred, bred, cidx, r);
  k_ab<<<256, 256, 0, stream>>>(r, Wcat, bcat, Ai, Aj);
  k_wt<<<768, 256, 0, stream>>>(Wx, WxT);
  k_tzr<<<512, 256, 0, stream>>>(Uzr, UzrT);
  k_tsh<<<256, 256, 0, stream>>>(Ush, UshT);
  k_gemm<<<dim3(1024, 6), 256, 0, stream>>>(Ai, Aj, WxT, bg, xg);
  k_wave2<<<64, 512, 0, stream>>>(xg, UzrT, UshT, Wt, bt, ym,
                                  couples, diag, ring, prod, cons);
  k_head<<<2048, 256, 0, stream>>>(diag, We, be, Wc, bc, pe, pc);
}

// Round 6
// 3569.871 us; speedup vs baseline: 2.3159x; 1.1474x over previous
//
#include <hip/hip_runtime.h>
#include <hip/hip_bf16.h>

typedef float f32x4 __attribute__((ext_vector_type(4)));
typedef __bf16 bf16x8 __attribute__((ext_vector_type(8)));
typedef __bf16 bf16x4 __attribute__((ext_vector_type(4)));

using as1c_t = __attribute__((address_space(1))) const char;
using as3_t  = __attribute__((address_space(3))) char;

static __device__ __forceinline__ float sigmoidf_(float x) {
  return 1.f / (1.f + __expf(-x));
}
static __device__ __forceinline__ float tanhf_(float x) {
  return 1.f - 2.f / (__expf(2.f * x) + 1.f);
}
static __device__ __forceinline__ __bf16 bfc(float x) { return (__bf16)x; }
static __device__ __forceinline__ float bf2f_(unsigned short u) {
  return __uint_as_float(((unsigned)u) << 16);
}

// ---------------- K1: r = gather(hidden) @ W_red + b_red ----------------
__global__ __launch_bounds__(256) void k_r(const float* __restrict__ hidden,
    const float* __restrict__ Wred, const float* __restrict__ bred,
    const int* __restrict__ cidx, float* __restrict__ r) {
  __shared__ float docsT[768][8];
  const int bx = blockIdx.x;
  const int b = bx >> 3, n0 = (bx & 7) * 8;
  const int t = threadIdx.x;
  #pragma unroll
  for (int g = 0; g < 8; ++g) {
    const int tok = cidx[b * 64 + n0 + g];
    const float* src = hidden + ((size_t)b * 512 + tok) * 768;
    for (int f = t; f < 768; f += 256) docsT[f][g] = src[f];
  }
  __syncthreads();
  float acc[8];
  #pragma unroll
  for (int g = 0; g < 8; ++g) acc[g] = bred[t];
  for (int f = 0; f < 768; ++f) {
    const float w = Wred[f * 256 + t];
    const float4 d0 = *(const float4*)&docsT[f][0];
    const float4 d1 = *(const float4*)&docsT[f][4];
    acc[0] = fmaf(d0.x, w, acc[0]); acc[1] = fmaf(d0.y, w, acc[1]);
    acc[2] = fmaf(d0.z, w, acc[2]); acc[3] = fmaf(d0.w, w, acc[3]);
    acc[4] = fmaf(d1.x, w, acc[4]); acc[5] = fmaf(d1.y, w, acc[5]);
    acc[6] = fmaf(d1.z, w, acc[6]); acc[7] = fmaf(d1.w, w, acc[7]);
  }
  #pragma unroll
  for (int g = 0; g < 8; ++g) r[((size_t)(b * 64 + n0 + g)) * 256 + t] = acc[g];
}

// ---------------- K2: Ai = r@Wcat[:256] + b_cat ; Aj = r@Wcat[256:] ----------------
__global__ __launch_bounds__(256) void k_ab(const float* __restrict__ r,
    const float* __restrict__ Wcat, const float* __restrict__ bcat,
    float* __restrict__ Ai, float* __restrict__ Aj) {
  __shared__ float rT[256][8];
  const int bx = blockIdx.x;
  const int b = bx >> 3, n0 = (bx & 7) * 8;
  const int t = threadIdx.x;
  #pragma unroll
  for (int g = 0; g < 8; ++g)
    rT[t][g] = r[((size_t)(b * 64 + n0 + g)) * 256 + t];
  __syncthreads();
  float ai[8], aj[8];
  #pragma unroll
  for (int g = 0; g < 8; ++g) { ai[g] = bcat[t]; aj[g] = 0.f; }
  for (int k = 0; k < 256; ++k) {
    const float w0 = Wcat[k * 256 + t];
    const float w1 = Wcat[(256 + k) * 256 + t];
    const float4 d0 = *(const float4*)&rT[k][0];
    const float4 d1 = *(const float4*)&rT[k][4];
    ai[0] = fmaf(d0.x, w0, ai[0]); aj[0] = fmaf(d0.x, w1, aj[0]);
    ai[1] = fmaf(d0.y, w0, ai[1]); aj[1] = fmaf(d0.y, w1, aj[1]);
    ai[2] = fmaf(d0.z, w0, ai[2]); aj[2] = fmaf(d0.z, w1, aj[2]);
    ai[3] = fmaf(d0.w, w0, ai[3]); aj[3] = fmaf(d0.w, w1, aj[3]);
    ai[4] = fmaf(d1.x, w0, ai[4]); aj[4] = fmaf(d1.x, w1, aj[4]);
    ai[5] = fmaf(d1.y, w0, ai[5]); aj[5] = fmaf(d1.y, w1, aj[5]);
    ai[6] = fmaf(d1.z, w0, ai[6]); aj[6] = fmaf(d1.z, w1, aj[6]);
    ai[7] = fmaf(d1.w, w0, ai[7]); aj[7] = fmaf(d1.w, w1, aj[7]);
  }
  #pragma unroll
  for (int g = 0; g < 8; ++g) {
    Ai[((size_t)(b * 64 + n0 + g)) * 256 + t] = ai[g];
    Aj[((size_t)(b * 64 + n0 + g)) * 256 + t] = aj[g];
  }
}

// ---------------- K3: weight transposes to bf16 ----------------
__global__ __launch_bounds__(256) void k_wt(const float* __restrict__ Wx,
                                            __hip_bfloat16* __restrict__ WxT) {
  const int n = blockIdx.x, k = threadIdx.x;
  WxT[n * 256 + k] = __float2bfloat16(Wx[k * 768 + n]);
}
__global__ __launch_bounds__(256) void k_tzr(const float* __restrict__ U,
                                             __hip_bfloat16* __restrict__ UT) {
  const int n = blockIdx.x, k = threadIdx.x;   // U[256][512] -> UT[512][256]
  UT[n * 256 + k] = __float2bfloat16(U[k * 512 + n]);
}
__global__ __launch_bounds__(256) void k_tsh(const float* __restrict__ U,
                                             __hip_bfloat16* __restrict__ UT) {
  const int n = blockIdx.x, k = threadIdx.x;   // U[256][256] -> UT[256][256]
  UT[n * 256 + k] = __float2bfloat16(U[k * 256 + n]);
}

// ---------------- K4: xg = relu(Ai[i]+Aj[j]) @ W_x + b_g  (bf16 MFMA) ----------------
__global__ __launch_bounds__(256) void k_gemm(const float* __restrict__ Ai,
    const float* __restrict__ Aj, const __hip_bfloat16* __restrict__ WxT,
    const float* __restrict__ bg, __hip_bfloat16* __restrict__ xg) {
  __shared__ alignas(128) char smem[32768];  // A tile 16KB | B tile 16KB
  char* const smA = smem;
  char* const smB = smem + 16384;
  const int t = threadIdx.x;
  const int lane = t & 63, w = t >> 6;
  const int wr = w >> 1, wc = w & 1;
  const int m0 = blockIdx.x * 128;
  const int n0 = blockIdx.y * 128;
  const char* const Wb = (const char*)WxT;

  const int b = m0 >> 12;
  const int ibase = (m0 >> 6) & 63;
  const int sRow4 = t >> 4;        // 0..15
  const int sK = (t & 15) * 4;     // float offset within 64-float k-chunk

  f32x4 acc[4][4];
  const f32x4 zero = {0.f, 0.f, 0.f, 0.f};
  #pragma unroll
  for (int a2 = 0; a2 < 4; ++a2)
    #pragma unroll
    for (int b2 = 0; b2 < 4; ++b2) acc[a2][b2] = zero;

  for (int s = 0; s < 4; ++s) {   // K-steps of 64 (K=256)
    const int k0 = s * 64;
    // A tile: coalesced (16 lanes cover one row's 256B), 8 passes of 16 rows
    #pragma unroll
    for (int p = 0; p < 8; ++p) {
      const int row = p * 16 + sRow4;
      const int ii2 = ibase + (row >> 6);
      const int jj2 = row & 63;
      const float4 av = *(const float4*)(Ai + ((size_t)b * 64 + ii2) * 256 + k0 + sK);
      const float4 cv = *(const float4*)(Aj + ((size_t)b * 64 + jj2) * 256 + k0 + sK);
      bf16x4 v;
      v[0] = bfc(fmaxf(av.x + cv.x, 0.f)); v[1] = bfc(fmaxf(av.y + cv.y, 0.f));
      v[2] = bfc(fmaxf(av.z + cv.z, 0.f)); v[3] = bfc(fmaxf(av.w + cv.w, 0.f));
      *(bf16x4*)(smA + row * 128 + (t & 15) * 8) = v;
    }
    // B tile via async global->LDS
    #pragma unroll
    for (int q = 0; q < 4; ++q) {
      const int chunk = w * 4 + q;
      const int tt2 = chunk * 1024 + lane * 16;
      const int row = tt2 >> 7;
      const int kb = tt2 & 0x7f;
      __builtin_amdgcn_global_load_lds(
          (as1c_t*)(Wb + (size_t)(n0 + row) * 512 + s * 128 + kb),
          (as3_t*)(smB + chunk * 1024), 16, 0, 0);
    }
    __syncthreads();
    #pragma unroll
    for (int kk = 0; kk < 2; ++kk) {
      bf16x8 af[4], bfr[4];
      const int kloc = kk * 64 + ((lane >> 4) << 4);
      #pragma unroll
      for (int ft = 0; ft < 4; ++ft) {
        const int rowa = wr * 64 + ft * 16 + (lane & 15);
        af[ft] = *(const bf16x8*)(smA + rowa * 128 + kloc);
      }
      #pragma unroll
      for (int fn = 0; fn < 4; ++fn) {
        const int rowb = wc * 64 + fn * 16 + (lane & 15);
        bfr[fn] = *(const bf16x8*)(smB + rowb * 128 + kloc);
      }
      #pragma unroll
      for (int ft = 0; ft < 4; ++ft)
        #pragma unroll
        for (int fn = 0; fn < 4; ++fn)
          acc[ft][fn] = __builtin_amdgcn_mfma_f32_16x16x32_bf16(
              af[ft], bfr[fn], acc[ft][fn], 0, 0, 0);
    }
    __syncthreads();
  }

  // epilogue: bounce through LDS for 64B-contiguous stores
  __hip_bfloat16* smC = (__hip_bfloat16*)smem;   // [128][128] bf16 = 32KB
  #pragma unroll
  for (int ft = 0; ft < 4; ++ft) {
    #pragma unroll
    for (int fn = 0; fn < 4; ++fn) {
      const int nl = wc * 64 + fn * 16 + (lane & 15);
      const float bias = bg[n0 + nl];
      #pragma unroll
      for (int jj = 0; jj < 4; ++jj) {
        const int ml = wr * 64 + ft * 16 + ((lane >> 4) << 2) + jj;
        smC[ml * 128 + nl] = __float2bfloat16(acc[ft][fn][jj] + bias);
      }
    }
  }
  __syncthreads();
  #pragma unroll
  for (int pp = 0; pp < 2; ++pp) {
    const int row = pp * 64 + (t >> 2);
    const int qtr = t & 3;
    #pragma unroll
    for (int q2 = 0; q2 < 4; ++q2) {
      const f32x4 v = *(const f32x4*)((const char*)smC + row * 256 + qtr * 64 + q2 * 16);
      *(f32x4*)((char*)xg + ((size_t)(m0 + row) * 768 + n0) * 2 + qtr * 64 + q2 * 16) = v;
    }
  }
}

// ---------------- K5: persistent MFMA wavefront 2-D GRU ----------------
// grid 64 (one block per row i), block 512 (8 waves; wave w owns cols [32w,32w+32))
// Sync protocol: ring data moves via agent-scope atomics (serviced at the
// coherence point, no cache invalidation needed). Producer: __syncthreads'
// implicit vmcnt(0) drain + RELEASE flag store. Consumer: t0-only relaxed
// poll + __syncthreads. NO __threadfence anywhere (it invalidated L2 and
// evicted the weights every cell — the round-4 29us/cell stall).
__global__ __launch_bounds__(512, 2) void k_wave2(
    const __hip_bfloat16* __restrict__ xg_,
    const __hip_bfloat16* __restrict__ UzT_,
    const __hip_bfloat16* __restrict__ UhT_,
    const float* __restrict__ Wt, const float* __restrict__ bt,
    const int* __restrict__ ym,
    float* __restrict__ couples, float* __restrict__ diagbuf,
    float* __restrict__ ring, int* __restrict__ prod, int* __restrict__ cons) {
  __shared__ float sL[32][264];     // s_left (f32)
  __shared__ float spf[32][264];    // s_prev (f32)
  __shared__ __bf16 sph[32][264];   // s_prev hi
  __shared__ __bf16 spl[32][264];   // s_prev lo
  __shared__ __bf16 rsh[32][264];   // r*s_prev (bf16)
  __shared__ float red[32][2];

  const __bf16* UzT = (const __bf16*)UzT_;
  const __bf16* UhT = (const __bf16*)UhT_;
  const unsigned short* xg = (const unsigned short*)xg_;
  const int t = threadIdx.x;
  const int i = blockIdx.x;
  const int wv = t >> 6, ln = t & 63;
  const int l15 = ln & 15, l4 = ln >> 4;
  const int cbase = wv * 32;

  for (int q = t; q < 32 * 264; q += 512) (&sL[0][0])[q] = 0.f;
  if (t < 64) red[t >> 1][t & 1] = 0.f;

  const int m0ph = t >> 4;           // phase-0 row (0..31)
  const int c0l = (t & 15) * 2;      // phase-0 col-pair base within 32-chunk
  int mrow[8]; int ymi_[8];
  const unsigned short* xgm[8];
  #pragma unroll
  for (int mt = 0; mt < 2; ++mt)
    #pragma unroll
    for (int jj = 0; jj < 4; ++jj) {
      const int idx = mt * 4 + jj;
      const int m = mt * 16 + l4 * 4 + jj;
      mrow[idx] = m;
      ymi_[idx] = ym[m * 64 + i];
      xgm[idx] = xg + ((size_t)m * 4096 + (size_t)i * 64) * 768;
    }
  float wtv[2][2];
  #pragma unroll
  for (int ntl = 0; ntl < 2; ++ntl) {
    const int cc2 = cbase + ntl * 16 + l15;
    wtv[ntl][0] = Wt[cc2 * 2 + 0]; wtv[ntl][1] = Wt[cc2 * 2 + 1];
  }
  const float* ring_rd = ring + (size_t)(i - 1) * 16384;
  float* ring_wr = ring + (size_t)i * 16384;
  const f32x4 z4 = {0.f, 0.f, 0.f, 0.f};
  __syncthreads();

  for (int j = 0; j < 64; ++j) {
    // xg preloads (issued early; consumed after matmuls)
    float xzf[16], xrf[16], xhf[16];
    #pragma unroll
    for (int idx = 0; idx < 8; ++idx) {
      const unsigned short* px = xgm[idx] + (size_t)j * 768;
      #pragma unroll
      for (int ntl = 0; ntl < 2; ++ntl) {
        const int cc2 = cbase + ntl * 16 + l15;
        xzf[idx * 2 + ntl] = bf2f_(px[cc2]);
        xrf[idx * 2 + ntl] = bf2f_(px[cc2 + 256]);
        xhf[idx * 2 + ntl] = bf2f_(px[cc2 + 512]);
      }
    }

    // ---- phase 0: wait for up-row (t0-only poll), build s_prev ----
    if (i > 0 && t == 0) {
      while (__hip_atomic_load(&prod[i - 1], __ATOMIC_RELAXED,
                               __HIP_MEMORY_SCOPE_AGENT) < j + 1)
        __builtin_amdgcn_s_sleep(1);
    }
    __syncthreads();                                      // (a) flag observed
    const float* rslot = ring_rd + (j & 1) * 8192;
    #pragma unroll
    for (int q = 0; q < 8; ++q) {
      const int c0 = q * 32 + c0l;
      float su0 = 0.f, su1 = 0.f;
      if (i > 0) {
        unsigned long long v = __hip_atomic_load(
            (unsigned long long*)(rslot + m0ph * 256 + c0),
            __ATOMIC_RELAXED, __HIP_MEMORY_SCOPE_AGENT);
        su0 = __uint_as_float((unsigned)v);
        su1 = __uint_as_float((unsigned)(v >> 32));
      }
      const float2 slv = *(const float2*)&sL[m0ph][c0];
      const float sp0 = 0.5f * (slv.x + su0), sp1 = 0.5f * (slv.y + su1);
      spf[m0ph][c0] = sp0; spf[m0ph][c0 + 1] = sp1;
      const __bf16 h0 = (__bf16)sp0, h1 = (__bf16)sp1;
      sph[m0ph][c0] = h0; sph[m0ph][c0 + 1] = h1;
      spl[m0ph][c0] = (__bf16)(sp0 - (float)h0);
      spl[m0ph][c0 + 1] = (__bf16)(sp1 - (float)h1);
    }
    __syncthreads();                                      // (b) sp ready (+ ring reads drained)
    if (i > 0 && t == 0)
      __hip_atomic_store(&cons[i], j + 1, __ATOMIC_RELAXED, __HIP_MEMORY_SCOPE_AGENT);

    // ---- zr matmul: [32,256]@[256,512] with hi/lo A-split ----
    f32x4 cz[2][2], cr[2][2];
    #pragma unroll
    for (int a2 = 0; a2 < 2; ++a2)
      #pragma unroll
      for (int b2 = 0; b2 < 2; ++b2) { cz[a2][b2] = z4; cr[a2][b2] = z4; }
    #pragma unroll
    for (int ks = 0; ks < 8; ++ks) {
      const int ab = ks * 64 + l4 * 16;
      const bf16x8 ah0 = *(const bf16x8*)((const char*)&sph[0][0] + (size_t)l15 * 528 + ab);
      const bf16x8 ah1 = *(const bf16x8*)((const char*)&sph[0][0] + (size_t)(16 + l15) * 528 + ab);
      const bf16x8 al0 = *(const bf16x8*)((const char*)&spl[0][0] + (size_t)l15 * 528 + ab);
      const bf16x8 al1 = *(const bf16x8*)((const char*)&spl[0][0] + (size_t)(16 + l15) * 528 + ab);
      const int ke = ks * 32 + l4 * 8;
      const bf16x8 bz0 = *(const bf16x8*)(UzT + (size_t)(cbase + l15) * 256 + ke);
      const bf16x8 bz1 = *(const bf16x8*)(UzT + (size_t)(cbase + 16 + l15) * 256 + ke);
      const bf16x8 br0 = *(const bf16x8*)(UzT + (size_t)(256 + cbase + l15) * 256 + ke);
      const bf16x8 br1 = *(const bf16x8*)(UzT + (size_t)(256 + cbase + 16 + l15) * 256 + ke);
      cz[0][0] = __builtin_amdgcn_mfma_f32_16x16x32_bf16(ah0, bz0, cz[0][0], 0, 0, 0);
      cz[0][0] = __builtin_amdgcn_mfma_f32_16x16x32_bf16(al0, bz0, cz[0][0], 0, 0, 0);
      cz[0][1] = __builtin_amdgcn_mfma_f32_16x16x32_bf16(ah0, bz1, cz[0][1], 0, 0, 0);
      cz[0][1] = __builtin_amdgcn_mfma_f32_16x16x32_bf16(al0, bz1, cz[0][1], 0, 0, 0);
      cz[1][0] = __builtin_amdgcn_mfma_f32_16x16x32_bf16(ah1, bz0, cz[1][0], 0, 0, 0);
      cz[1][0] = __builtin_amdgcn_mfma_f32_16x16x32_bf16(al1, bz0, cz[1][0], 0, 0, 0);
      cz[1][1] = __builtin_amdgcn_mfma_f32_16x16x32_bf16(ah1, bz1, cz[1][1], 0, 0, 0);
      cz[1][1] = __builtin_amdgcn_mfma_f32_16x16x32_bf16(al1, bz1, cz[1][1], 0, 0, 0);
      cr[0][0] = __builtin_amdgcn_mfma_f32_16x16x32_bf16(ah0, br0, cr[0][0], 0, 0, 0);
      cr[0][0] = __builtin_amdgcn_mfma_f32_16x16x32_bf16(al0, br0, cr[0][0], 0, 0, 0);
      cr[0][1] = __builtin_amdgcn_mfma_f32_16x16x32_bf16(ah0, br1, cr[0][1], 0, 0, 0);
      cr[0][1] = __builtin_amdgcn_mfma_f32_16x16x32_bf16(al0, br1, cr[0][1], 0, 0, 0);
      cr[1][0] = __builtin_amdgcn_mfma_f32_16x16x32_bf16(ah1, br0, cr[1][0], 0, 0, 0);
      cr[1][0] = __builtin_amdgcn_mfma_f32_16x16x32_bf16(al1, br0, cr[1][0], 0, 0, 0);
      cr[1][1] = __builtin_amdgcn_mfma_f32_16x16x32_bf16(ah1, br1, cr[1][1], 0, 0, 0);
      cr[1][1] = __builtin_amdgcn_mfma_f32_16x16x32_bf16(al1, br1, cr[1][1], 0, 0, 0);
    }

    // ---- gates + rs ----
    float zz[16];
    #pragma unroll
    for (int mt = 0; mt < 2; ++mt)
      #pragma unroll
      for (int ntl = 0; ntl < 2; ++ntl)
        #pragma unroll
        for (int jj = 0; jj < 4; ++jj) {
          const int fi = (mt * 4 + jj) * 2 + ntl;
          const int m = mt * 16 + l4 * 4 + jj;
          const int cc2 = cbase + ntl * 16 + l15;
          const float zv = sigmoidf_(cz[mt][ntl][jj] + xzf[fi]);
          const float rv = sigmoidf_(cr[mt][ntl][jj] + xrf[fi]);
          zz[fi] = zv;
          rsh[m][cc2] = (__bf16)(rv * spf[m][cc2]);
        }
    if (i < 63 && t == 0) {
      while (__hip_atomic_load(&cons[i + 1], __ATOMIC_RELAXED,
                               __HIP_MEMORY_SCOPE_AGENT) < j - 1)
        __builtin_amdgcn_s_sleep(1);
    }
    __syncthreads();                                      // (e) rs ready, ring slot free

    // ---- h matmul: [32,256]@[256,256] ----
    f32x4 ch[2][2];
    #pragma unroll
    for (int a2 = 0; a2 < 2; ++a2)
      #pragma unroll
      for (int b2 = 0; b2 < 2; ++b2) ch[a2][b2] = z4;
    #pragma unroll
    for (int ks = 0; ks < 8; ++ks) {
      const int ab = ks * 64 + l4 * 16;
      const bf16x8 a0 = *(const bf16x8*)((const char*)&rsh[0][0] + (size_t)l15 * 528 + ab);
      const bf16x8 a1 = *(const bf16x8*)((const char*)&rsh[0][0] + (size_t)(16 + l15) * 528 + ab);
      const int ke = ks * 32 + l4 * 8;
      const bf16x8 b0 = *(const bf16x8*)(UhT + (size_t)(cbase + l15) * 256 + ke);
      const bf16x8 b1 = *(const bf16x8*)(UhT + (size_t)(cbase + 16 + l15) * 256 + ke);
      ch[0][0] = __builtin_amdgcn_mfma_f32_16x16x32_bf16(a0, b0, ch[0][0], 0, 0, 0);
      ch[0][1] = __builtin_amdgcn_mfma_f32_16x16x32_bf16(a0, b1, ch[0][1], 0, 0, 0);
      ch[1][0] = __builtin_amdgcn_mfma_f32_16x16x32_bf16(a1, b0, ch[1][0], 0, 0, 0);
      ch[1][1] = __builtin_amdgcn_mfma_f32_16x16x32_bf16(a1, b1, ch[1][1], 0, 0, 0);
    }

    // ---- update + ring publish + couples ----
    int ymj_[8];
    #pragma unroll
    for (int idx = 0; idx < 8; ++idx) ymj_[idx] = ym[mrow[idx] * 64 + j];
    float* wslot = ring_wr + (j & 1) * 8192;
    float cp[2][4][2];
    #pragma unroll
    for (int mt = 0; mt < 2; ++mt)
      #pragma unroll
      for (int jj = 0; jj < 4; ++jj) { cp[mt][jj][0] = 0.f; cp[mt][jj][1] = 0.f; }
    #pragma unroll
    for (int mt = 0; mt < 2; ++mt)
      #pragma unroll
      for (int ntl = 0; ntl < 2; ++ntl)
        #pragma unroll
        for (int jj = 0; jj < 4; ++jj) {
          const int fi = (mt * 4 + jj) * 2 + ntl;
          const int m = mt * 16 + l4 * 4 + jj;
          const int cc2 = cbase + ntl * 16 + l15;
          const float hv = tanhf_(ch[mt][ntl][jj] + xhf[fi]);
          const float spv = spf[m][cc2];
          float sv = spv + zz[fi] * (hv - spv);
          sv *= (float)(ymi_[mt * 4 + jj] & ymj_[mt * 4 + jj]);
          sL[m][cc2] = sv;
          if (i < 63)
            __hip_atomic_store(wslot + m * 256 + cc2, sv,
                               __ATOMIC_RELAXED, __HIP_MEMORY_SCOPE_AGENT);
          if (j == i) diagbuf[((size_t)m * 64 + i) * 256 + cc2] = sv;
          cp[mt][jj][0] = fmaf(sv, wtv[ntl][0], cp[mt][jj][0]);
          cp[mt][jj][1] = fmaf(sv, wtv[ntl][1], cp[mt][jj][1]);
        }
    #pragma unroll
    for (int mt = 0; mt < 2; ++mt)
      #pragma unroll
      for (int jj = 0; jj < 4; ++jj)
        #pragma unroll
        for (int o = 0; o < 2; ++o) {
          float x = cp[mt][jj][o];
          x += __shfl_xor(x, 1); x += __shfl_xor(x, 2);
          x += __shfl_xor(x, 4); x += __shfl_xor(x, 8);
          cp[mt][jj][o] = x;
        }
    if (l15 == 0) {
      #pragma unroll
      for (int mt = 0; mt < 2; ++mt)
        #pragma unroll
        for (int jj = 0; jj < 4; ++jj) {
          const int m = mt * 16 + l4 * 4 + jj;
          atomicAdd(&red[m][0], cp[mt][jj][0]);
          atomicAdd(&red[m][1], cp[mt][jj][1]);
        }
    }
    __syncthreads();   // (h) all waves' ring stores drained (implicit vmcnt(0))
    // flag first (release: cheap, vmcnt already 0), then epilogue stores
    if (i < 63 && t == 0)
      __hip_atomic_store(&prod[i], j + 1, __ATOMIC_RELEASE, __HIP_MEMORY_SCOPE_AGENT);
    if (t < 64) {
      const int m = t >> 1, o = t & 1;
      couples[((size_t)m * 4096 + (size_t)i * 64 + j) * 2 + o] = red[m][o] + bt[o];
      red[m][o] = 0.f;
    }
  }
}

// ---------------- K6: pred_e / pred_c from diagonal states ----------------
__global__ __launch_bounds__(256) void k_head(const float* __restrict__ diagbuf,
    const float* __restrict__ We, const float* __restrict__ be,
    const float* __restrict__ Wc, const float* __restrict__ bc,
    float* __restrict__ pe, float* __restrict__ pc) {
  __shared__ float red[4][4];
  const int bn = blockIdx.x;
  const int t = threadIdx.x;
  const float s = diagbuf[(size_t)bn * 256 + t];
  float v[4] = { s * We[t * 2], s * We[t * 2 + 1], s * Wc[t * 2], s * Wc[t * 2 + 1] };
  #pragma unroll
  for (int q = 0; q < 4; ++q) {
    float x = v[q];
    x += __shfl_xor(x, 1);  x += __shfl_xor(x, 2);  x += __shfl_xor(x, 4);
    x += __shfl_xor(x, 8);  x += __shfl_xor(x, 16); x += __shfl_xor(x, 32);
    v[q] = x;
  }
  if ((t & 63) == 0) {
    #pragma unroll
    for (int q = 0; q < 4; ++q) red[t >> 6][q] = v[q];
  }
  __syncthreads();
  if (t < 4) {
    const float x = red[0][t] + red[1][t] + red[2][t] + red[3][t];
    if (t < 2) pe[bn * 2 + t] = x + be[t];
    else       pc[bn * 2 + (t - 2)] = x + bc[t - 2];
  }
}

extern "C" void kernel_launch(void* const* d_in, const int* in_sizes, int n_in,
                              void* d_out, int out_size, void* d_ws, size_t ws_size,
                              hipStream_t stream) {
  const float* hidden = (const float*)d_in[0];
  const float* Wred = (const float*)d_in[1];
  const float* bred = (const float*)d_in[2];
  const float* Wcat = (const float*)d_in[3];
  const float* bcat = (const float*)d_in[4];
  const float* Wx   = (const float*)d_in[5];
  const float* Uzr  = (const float*)d_in[6];
  const float* Ush  = (const float*)d_in[7];
  const float* bg   = (const float*)d_in[8];
  const float* We   = (const float*)d_in[9];
  const float* be   = (const float*)d_in[10];
  const float* Wc   = (const float*)d_in[11];
  const float* bc   = (const float*)d_in[12];
  const float* Wt   = (const float*)d_in[13];
  const float* bt   = (const float*)d_in[14];
  const int* cidx   = (const int*)d_in[15];
  const int* ym     = (const int*)d_in[16];

  // ---- workspace layout (max used: 212,602,880 B < proven 214,302,720) ----
  char* ws = (char*)d_ws;
  float* Ai   = (float*)(ws);                          // 2 MB
  float* Aj   = (float*)(ws + 2097152);                // 2 MB
  float* diag = (float*)(ws + 4194304);                // 2 MB
  __hip_bfloat16* WxT  = (__hip_bfloat16*)(ws + 6291456);   // 393,216
  __hip_bfloat16* UzrT = (__hip_bfloat16*)(ws + 6684672);   // 262,144
  __hip_bfloat16* UshT = (__hip_bfloat16*)(ws + 6946816);   // 131,072
  int* prod = (int*)(ws + 7077888);                    // flags: 4 KB
  int* cons = (int*)(ws + 7077888 + 1024);
  float* ring = (float*)(ws + 7081984);                // 64*2*32KB = 4 MB
  float* r = ring;                                     // alias: r dead before k_wave2
  __hip_bfloat16* xg = (__hip_bfloat16*)(ws + 11276288);    // 192 MiB

  float* couples = (float*)d_out;          // (32,64,64,2)
  float* pe = couples + 262144;            // (32,64,2)
  float* pc = couples + 266240;            // (32,64,2)

  hipMemsetAsync(ws + 7077888, 0, 4096, stream);
  k_r<<<256, 256, 0, stream>>>(hidden, Wred, bred, cidx, r);
  k_ab<<<256, 256, 0, stream>>>(r, Wcat, bcat, Ai, Aj);
  k_wt<<<768, 256, 0, stream>>>(Wx, WxT);
  k_tzr<<<512, 256, 0, stream>>>(Uzr, UzrT);
  k_tsh<<<256, 256, 0, stream>>>(Ush, UshT);
  k_gemm<<<dim3(1024, 6), 256, 0, stream>>>(Ai, Aj, WxT, bg, xg);
  k_wave2<<<64, 512, 0, stream>>>(xg, UzrT, UshT, Wt, bt, ym,
                                  couples, diag, ring, prod, cons);
  k_head<<<2048, 256, 0, stream>>>(diag, We, be, Wc, bc, pe, pc);
}